// Round 1
// baseline (100.055 us; speedup 1.0000x reference)
//
#include <hip/hip_runtime.h>

#define BB 8
#define SS 4096
#define NN 1024
#define DD 1024
#define NUM_WIDTH 64
#define WIDTH_DIM 64
#define OUTD (DD + WIDTH_DIM)   // 1088

// Kernel 1: logits[b,s] = dot(seq[b,s,:], w) + bias
// One wave (64 lanes) per row; block = 256 threads = 4 rows.
__global__ __launch_bounds__(256) void logits_kernel(const float* __restrict__ seq,
                                                     const float* __restrict__ w,
                                                     const float* __restrict__ bias,
                                                     float* __restrict__ logits) {
    int wave = threadIdx.x >> 6;
    int lane = threadIdx.x & 63;
    long long row = (long long)blockIdx.x * 4 + wave;   // < B*S = 32768
    const float4* s4 = (const float4*)(seq + row * DD);
    const float4* w4 = (const float4*)w;
    float sum = 0.f;
    #pragma unroll
    for (int j = 0; j < 4; ++j) {
        float4 v  = s4[lane + 64 * j];
        float4 ww = w4[lane + 64 * j];
        sum += v.x * ww.x + v.y * ww.y + v.z * ww.z + v.w * ww.w;
    }
    #pragma unroll
    for (int m = 32; m >= 1; m >>= 1)
        sum += __shfl_xor(sum, m, 64);
    if (lane == 0) logits[row] = sum + bias[0];
}

// Kernel 2: one block per span (b,n). Softmax over <=32 logits in wave 0,
// then all 256 threads do float4 weighted gather-sum over span rows.
__global__ __launch_bounds__(256) void span_kernel(const float* __restrict__ seq,
                                                   const int* __restrict__ idx,
                                                   const float* __restrict__ logits,
                                                   const float* __restrict__ wemb,
                                                   float* __restrict__ out) {
    int bn  = blockIdx.x;       // b*N + n
    int b   = bn >> 10;         // N = 1024
    int tid = threadIdx.x;

    int start = idx[bn * 2 + 0];
    int end   = idx[bn * 2 + 1];
    bool valid = (start >= 0) && (end >= start);
    int s0 = start > 0 ? start : 0;
    int e0 = end < (SS - 1) ? end : (SS - 1);
    int L  = valid ? (e0 - s0 + 1) : 0;
    if (L < 0) L = 0;
    if (L > 32) L = 32;         // data guarantees width < 32

    __shared__ float p_lds[32];

    if (tid < 64) {
        float v = -INFINITY;
        if (tid < L) v = logits[b * SS + s0 + tid];
        float m = v;
        #pragma unroll
        for (int d = 32; d >= 1; d >>= 1)
            m = fmaxf(m, __shfl_xor(m, d, 64));
        float e = (tid < L) ? expf(v - m) : 0.f;
        float sm = e;
        #pragma unroll
        for (int d = 32; d >= 1; d >>= 1)
            sm += __shfl_xor(sm, d, 64);
        float p = (sm > 0.f) ? e / sm : 0.f;
        if (tid < 32) p_lds[tid] = p;
    }
    __syncthreads();

    // Weighted sum over span rows; each thread owns 4 consecutive columns.
    float4 acc = make_float4(0.f, 0.f, 0.f, 0.f);
    const float4* s4 = (const float4*)(seq + ((long long)b * SS + s0) * DD);
    for (int r = 0; r < L; ++r) {
        float pr = p_lds[r];               // LDS broadcast
        float4 v = s4[(long long)r * (DD / 4) + tid];
        acc.x += pr * v.x;
        acc.y += pr * v.y;
        acc.z += pr * v.z;
        acc.w += pr * v.w;
    }

    float4* o4 = (float4*)(out + (long long)bn * OUTD);
    o4[tid] = acc;                          // acc == 0 when invalid/empty

    if (tid < WIDTH_DIM) {
        int wdt = end - start;
        if (wdt < 0) wdt = 0;
        if (wdt > NUM_WIDTH - 1) wdt = NUM_WIDTH - 1;
        out[(long long)bn * OUTD + DD + tid] = wemb[wdt * WIDTH_DIM + tid];
    }
}

extern "C" void kernel_launch(void* const* d_in, const int* in_sizes, int n_in,
                              void* d_out, int out_size, void* d_ws, size_t ws_size,
                              hipStream_t stream) {
    const float* seq  = (const float*)d_in[0];
    const int*   idx  = (const int*)d_in[1];
    const float* w    = (const float*)d_in[2];
    const float* bias = (const float*)d_in[3];
    const float* wemb = (const float*)d_in[4];
    float* out = (float*)d_out;
    float* logits = (float*)d_ws;   // B*S floats = 128 KB

    logits_kernel<<<(BB * SS) / 4, 256, 0, stream>>>(seq, w, bias, logits);
    span_kernel<<<BB * NN, 256, 0, stream>>>(seq, idx, logits, wemb, out);
}

// Round 2
// 70.045 us; speedup vs baseline: 1.4284x; 1.4284x over previous
//
#include <hip/hip_runtime.h>

#define BB 8
#define SS 4096
#define NN 1024
#define DD 1024
#define NUM_WIDTH 64
#define WIDTH_DIM 64
#define OUTD (DD + WIDTH_DIM)   // 1088
#define NBUCK 128               // per-batch start buckets (start >> 5)
#define NBINS (BB * NBUCK)      // 1024

// ---- counting sort of span ids by (batch, start>>5) ----

__global__ void init_bins(int* __restrict__ bins) {
    bins[blockIdx.x * 256 + threadIdx.x] = 0;
}

__global__ void hist_kernel(const int* __restrict__ idx, int* __restrict__ bins) {
    int bn = blockIdx.x * 256 + threadIdx.x;          // < 8192
    int start = idx[bn * 2];
    int b = bn >> 10;
    int s0 = start > 0 ? start : 0;
    if (s0 > SS - 1) s0 = SS - 1;
    atomicAdd(&bins[b * NBUCK + (s0 >> 5)], 1);
}

__global__ __launch_bounds__(1024) void scan_kernel(int* __restrict__ bins) {
    __shared__ int lds[NBINS];
    int tid = threadIdx.x;
    lds[tid] = bins[tid];
    __syncthreads();
    for (int off = 1; off < NBINS; off <<= 1) {
        int add = (tid >= off) ? lds[tid - off] : 0;
        __syncthreads();
        lds[tid] += add;
        __syncthreads();
    }
    bins[tid] = (tid > 0) ? lds[tid - 1] : 0;          // exclusive scan
}

__global__ void scatter_kernel(const int* __restrict__ idx, int* __restrict__ bins,
                               int* __restrict__ perm) {
    int bn = blockIdx.x * 256 + threadIdx.x;
    int start = idx[bn * 2];
    int b = bn >> 10;
    int s0 = start > 0 ? start : 0;
    if (s0 > SS - 1) s0 = SS - 1;
    int pos = atomicAdd(&bins[b * NBUCK + (s0 >> 5)], 1);
    perm[pos] = bn;
}

// ---- fused span kernel: logits + softmax + weighted gather + width emb ----

__global__ __launch_bounds__(256) void span_kernel(const float* __restrict__ seq,
                                                   const int* __restrict__ idx,
                                                   const float* __restrict__ w,
                                                   const float* __restrict__ wemb,
                                                   const int* __restrict__ perm,
                                                   float* __restrict__ out) {
    // XCD-chunked swizzle: XCD k (round-robin on blockIdx%8) gets a
    // contiguous range of the sorted span order -> L2 locality per XCD.
    int swz = (blockIdx.x & 7) * (BB * NN / 8) + (blockIdx.x >> 3);
    int bn  = perm[swz];
    int b   = bn >> 10;
    int tid = threadIdx.x;
    int wave = tid >> 6;
    int lane = tid & 63;

    int start = idx[bn * 2 + 0];
    int end   = idx[bn * 2 + 1];
    int s0 = start > 0 ? start : 0;
    int e0 = end < (SS - 1) ? end : (SS - 1);
    int L  = (start >= 0 && end >= start) ? (e0 - s0 + 1) : 0;
    if (L < 0) L = 0;
    if (L > 32) L = 32;

    __shared__ float p_lds[32];

    const float4* s4 = (const float4*)(seq + ((long long)b * SS + s0) * DD);
    const float4* w4 = (const float4*)w;

    // pass 1: per-row logit, rows strided across the 4 waves
    float4 wr0 = w4[lane], wr1 = w4[64 + lane], wr2 = w4[128 + lane], wr3 = w4[192 + lane];
    for (int r = wave; r < L; r += 4) {
        const float4* row = s4 + (long long)r * (DD / 4);
        float4 a0 = row[lane], a1 = row[64 + lane], a2 = row[128 + lane], a3 = row[192 + lane];
        float sum = a0.x * wr0.x + a0.y * wr0.y + a0.z * wr0.z + a0.w * wr0.w
                  + a1.x * wr1.x + a1.y * wr1.y + a1.z * wr1.z + a1.w * wr1.w
                  + a2.x * wr2.x + a2.y * wr2.y + a2.z * wr2.z + a2.w * wr2.w
                  + a3.x * wr3.x + a3.y * wr3.y + a3.z * wr3.z + a3.w * wr3.w;
        #pragma unroll
        for (int m = 32; m >= 1; m >>= 1)
            sum += __shfl_xor(sum, m, 64);
        if (lane == 0) p_lds[r] = sum;
    }
    __syncthreads();

    // softmax over the <=32 logits (wave 0)
    if (tid < 64) {
        float v = (tid < L) ? p_lds[tid] : -INFINITY;
        float m = v;
        #pragma unroll
        for (int d = 32; d >= 1; d >>= 1)
            m = fmaxf(m, __shfl_xor(m, d, 64));
        float e = (tid < L) ? expf(v - m) : 0.f;
        float sm = e;
        #pragma unroll
        for (int d = 32; d >= 1; d >>= 1)
            sm += __shfl_xor(sm, d, 64);
        float p = (sm > 0.f) ? e / sm : 0.f;
        if (tid < 32) p_lds[tid] = p;
    }
    __syncthreads();

    // pass 2: weighted sum; rows are L2-hot from pass 1. 4-deep unroll for MLP.
    float4 acc = make_float4(0.f, 0.f, 0.f, 0.f);
    int r = 0;
    for (; r + 4 <= L; r += 4) {
        float4 v0 = s4[(long long)(r + 0) * (DD / 4) + tid];
        float4 v1 = s4[(long long)(r + 1) * (DD / 4) + tid];
        float4 v2 = s4[(long long)(r + 2) * (DD / 4) + tid];
        float4 v3 = s4[(long long)(r + 3) * (DD / 4) + tid];
        float p0 = p_lds[r + 0], p1 = p_lds[r + 1], p2 = p_lds[r + 2], p3 = p_lds[r + 3];
        acc.x += p0 * v0.x + p1 * v1.x + p2 * v2.x + p3 * v3.x;
        acc.y += p0 * v0.y + p1 * v1.y + p2 * v2.y + p3 * v3.y;
        acc.z += p0 * v0.z + p1 * v1.z + p2 * v2.z + p3 * v3.z;
        acc.w += p0 * v0.w + p1 * v1.w + p2 * v2.w + p3 * v3.w;
    }
    for (; r < L; ++r) {
        float pr = p_lds[r];
        float4 v = s4[(long long)r * (DD / 4) + tid];
        acc.x += pr * v.x;
        acc.y += pr * v.y;
        acc.z += pr * v.z;
        acc.w += pr * v.w;
    }

    float4* o4 = (float4*)(out + (long long)bn * OUTD);
    o4[tid] = acc;

    if (tid < WIDTH_DIM) {
        int wdt = end - start;
        if (wdt < 0) wdt = 0;
        if (wdt > NUM_WIDTH - 1) wdt = NUM_WIDTH - 1;
        out[(long long)bn * OUTD + DD + tid] = wemb[wdt * WIDTH_DIM + tid];
    }
}

extern "C" void kernel_launch(void* const* d_in, const int* in_sizes, int n_in,
                              void* d_out, int out_size, void* d_ws, size_t ws_size,
                              hipStream_t stream) {
    const float* seq  = (const float*)d_in[0];
    const int*   idx  = (const int*)d_in[1];
    const float* w    = (const float*)d_in[2];
    const float* wemb = (const float*)d_in[4];
    float* out = (float*)d_out;

    int* bins = (int*)d_ws;              // NBINS ints
    int* perm = bins + NBINS;            // B*N ints

    init_bins<<<NBINS / 256, 256, 0, stream>>>(bins);
    hist_kernel<<<(BB * NN) / 256, 256, 0, stream>>>(idx, bins);
    scan_kernel<<<1, NBINS, 0, stream>>>(bins);
    scatter_kernel<<<(BB * NN) / 256, 256, 0, stream>>>(idx, bins, perm);
    span_kernel<<<BB * NN, 256, 0, stream>>>(seq, idx, w, wemb, perm, out);
}

// Round 3
// 50.902 us; speedup vs baseline: 1.9657x; 1.3761x over previous
//
#include <hip/hip_runtime.h>

#define BB 8
#define SS 4096
#define NN 1024
#define DD 1024
#define NUM_WIDTH 64
#define WIDTH_DIM 64
#define OUTD (DD + WIDTH_DIM)   // 1088
#define NBUCK 128               // per-batch start buckets (start >> 5)
#define NBINS (BB * NBUCK)      // 1024

// ---- counting sort of span ids by (batch, start>>5) ----

__global__ void init_bins(int* __restrict__ bins) {
    bins[blockIdx.x * 256 + threadIdx.x] = 0;
}

__global__ void hist_kernel(const int* __restrict__ idx, int* __restrict__ bins) {
    int bn = blockIdx.x * 256 + threadIdx.x;          // < 8192
    int start = idx[bn * 2];
    int b = bn >> 10;
    int s0 = start > 0 ? start : 0;
    if (s0 > SS - 1) s0 = SS - 1;
    atomicAdd(&bins[b * NBUCK + (s0 >> 5)], 1);
}

__global__ __launch_bounds__(1024) void scan_kernel(int* __restrict__ bins) {
    __shared__ int lds[NBINS];
    int tid = threadIdx.x;
    lds[tid] = bins[tid];
    __syncthreads();
    for (int off = 1; off < NBINS; off <<= 1) {
        int add = (tid >= off) ? lds[tid - off] : 0;
        __syncthreads();
        lds[tid] += add;
        __syncthreads();
    }
    bins[tid] = (tid > 0) ? lds[tid - 1] : 0;          // exclusive scan
}

__global__ void scatter_kernel(const int* __restrict__ idx, int* __restrict__ bins,
                               int* __restrict__ perm) {
    int bn = blockIdx.x * 256 + threadIdx.x;
    int start = idx[bn * 2];
    int b = bn >> 10;
    int s0 = start > 0 ? start : 0;
    if (s0 > SS - 1) s0 = SS - 1;
    int pos = atomicAdd(&bins[b * NBUCK + (s0 >> 5)], 1);
    perm[pos] = bn;
}

// ---- fused span kernel: single-pass online softmax, rows read ONCE ----

__global__ __launch_bounds__(256) void span_kernel(const float* __restrict__ seq,
                                                   const int* __restrict__ idx,
                                                   const float* __restrict__ w,
                                                   const float* __restrict__ wemb,
                                                   const int* __restrict__ perm,
                                                   float* __restrict__ out) {
    // XCD-chunked swizzle over the sorted span order -> per-XCD L2 locality.
    int swz = (blockIdx.x & 7) * (BB * NN / 8) + (blockIdx.x >> 3);
    int bn  = perm[swz];
    int b   = bn >> 10;
    int tid = threadIdx.x;
    int wave = tid >> 6;
    int lane = tid & 63;

    int start = idx[bn * 2 + 0];
    int end   = idx[bn * 2 + 1];
    int s0 = start > 0 ? start : 0;
    int e0 = end < (SS - 1) ? end : (SS - 1);
    int L  = (start >= 0 && end >= start) ? (e0 - s0 + 1) : 0;
    if (L < 0) L = 0;
    if (L > 32) L = 32;

    __shared__ float lds_acc[4][DD];     // per-wave unscaled accumulators
    __shared__ float lds_m[4], lds_z[4];

    const float4* s4 = (const float4*)(seq + ((long long)b * SS + s0) * DD);
    const float4* w4 = (const float4*)w;
    float4 wr0 = w4[lane], wr1 = w4[64 + lane], wr2 = w4[128 + lane], wr3 = w4[192 + lane];

    float m = -INFINITY, Z = 0.f;
    float4 acc0 = make_float4(0.f, 0.f, 0.f, 0.f);
    float4 acc1 = acc0, acc2 = acc0, acc3 = acc0;

    for (int r = wave; r < L; r += 4) {
        const float4* row = s4 + (long long)r * (DD / 4);
        float4 a0 = row[lane], a1 = row[64 + lane], a2 = row[128 + lane], a3 = row[192 + lane];
        float dot = a0.x * wr0.x + a0.y * wr0.y + a0.z * wr0.z + a0.w * wr0.w
                  + a1.x * wr1.x + a1.y * wr1.y + a1.z * wr1.z + a1.w * wr1.w
                  + a2.x * wr2.x + a2.y * wr2.y + a2.z * wr2.z + a2.w * wr2.w
                  + a3.x * wr3.x + a3.y * wr3.y + a3.z * wr3.z + a3.w * wr3.w;
        #pragma unroll
        for (int d = 32; d >= 1; d >>= 1)
            dot += __shfl_xor(dot, d, 64);
        // dot is wave-uniform now; branch below is wave-uniform (no divergence)
        if (dot > m) {
            float f = __expf(m - dot);   // m==-inf -> f=0, zeroes stale state
            Z *= f;
            acc0.x *= f; acc0.y *= f; acc0.z *= f; acc0.w *= f;
            acc1.x *= f; acc1.y *= f; acc1.z *= f; acc1.w *= f;
            acc2.x *= f; acc2.y *= f; acc2.z *= f; acc2.w *= f;
            acc3.x *= f; acc3.y *= f; acc3.z *= f; acc3.w *= f;
            m = dot;
        }
        float e = __expf(dot - m);
        Z += e;
        acc0.x += e * a0.x; acc0.y += e * a0.y; acc0.z += e * a0.z; acc0.w += e * a0.w;
        acc1.x += e * a1.x; acc1.y += e * a1.y; acc1.z += e * a1.z; acc1.w += e * a1.w;
        acc2.x += e * a2.x; acc2.y += e * a2.y; acc2.z += e * a2.z; acc2.w += e * a2.w;
        acc3.x += e * a3.x; acc3.y += e * a3.y; acc3.z += e * a3.z; acc3.w += e * a3.w;
    }

    // per-wave partials -> LDS (unscaled; scale applied during combine)
    if (lane == 0) { lds_m[wave] = m; lds_z[wave] = Z; }
    float4* la = (float4*)lds_acc[wave];
    la[lane] = acc0; la[64 + lane] = acc1; la[128 + lane] = acc2; la[192 + lane] = acc3;
    __syncthreads();

    float m0 = lds_m[0], m1 = lds_m[1], m2 = lds_m[2], m3 = lds_m[3];
    float mg = fmaxf(fmaxf(m0, m1), fmaxf(m2, m3));
    float f0 = (m0 == -INFINITY) ? 0.f : __expf(m0 - mg);
    float f1 = (m1 == -INFINITY) ? 0.f : __expf(m1 - mg);
    float f2 = (m2 == -INFINITY) ? 0.f : __expf(m2 - mg);
    float f3 = (m3 == -INFINITY) ? 0.f : __expf(m3 - mg);
    float Zg = f0 * lds_z[0] + f1 * lds_z[1] + f2 * lds_z[2] + f3 * lds_z[3];
    float inv = (Zg > 0.f) ? 1.0f / Zg : 0.f;

    float4 r0 = ((float4*)lds_acc[0])[tid];
    float4 r1 = ((float4*)lds_acc[1])[tid];
    float4 r2 = ((float4*)lds_acc[2])[tid];
    float4 r3 = ((float4*)lds_acc[3])[tid];
    float4 o;
    o.x = (f0 * r0.x + f1 * r1.x + f2 * r2.x + f3 * r3.x) * inv;
    o.y = (f0 * r0.y + f1 * r1.y + f2 * r2.y + f3 * r3.y) * inv;
    o.z = (f0 * r0.z + f1 * r1.z + f2 * r2.z + f3 * r3.z) * inv;
    o.w = (f0 * r0.w + f1 * r1.w + f2 * r2.w + f3 * r3.w) * inv;

    float4* o4 = (float4*)(out + (long long)bn * OUTD);
    o4[tid] = o;

    if (tid < WIDTH_DIM) {
        int wdt = end - start;
        if (wdt < 0) wdt = 0;
        if (wdt > NUM_WIDTH - 1) wdt = NUM_WIDTH - 1;
        out[(long long)bn * OUTD + DD + tid] = wemb[wdt * WIDTH_DIM + tid];
    }
}

extern "C" void kernel_launch(void* const* d_in, const int* in_sizes, int n_in,
                              void* d_out, int out_size, void* d_ws, size_t ws_size,
                              hipStream_t stream) {
    const float* seq  = (const float*)d_in[0];
    const int*   idx  = (const int*)d_in[1];
    const float* w    = (const float*)d_in[2];
    const float* wemb = (const float*)d_in[4];
    float* out = (float*)d_out;

    int* bins = (int*)d_ws;              // NBINS ints
    int* perm = bins + NBINS;            // B*N ints

    init_bins<<<NBINS / 256, 256, 0, stream>>>(bins);
    hist_kernel<<<(BB * NN) / 256, 256, 0, stream>>>(idx, bins);
    scan_kernel<<<1, NBINS, 0, stream>>>(bins);
    scatter_kernel<<<(BB * NN) / 256, 256, 0, stream>>>(idx, bins, perm);
    span_kernel<<<BB * NN, 256, 0, stream>>>(seq, idx, w, wemb, perm, out);
}